// Round 11
// baseline (333.084 us; speedup 1.0000x reference)
//
#include <hip/hip_runtime.h>
#include <hip/hip_bf16.h>

typedef __attribute__((ext_vector_type(8))) short bfrag8;
typedef __attribute__((ext_vector_type(4))) float f32x4;
typedef __attribute__((ext_vector_type(4))) unsigned int u32x4;

#define IS2_SCALE 0.84932180028801907f   /* sqrt(0.5*log2(e)): exp2(-(u)^2)=exp(-t^2/2) */
#define W1_SCALE  0.46971724f            /* 1/(sqrt(2*3.14159)*IS2_SCALE): folds coef into W1 */

#if __has_builtin(__builtin_amdgcn_exp2f)
#define GEXP(x) __builtin_amdgcn_exp2f(x)
#else
__device__ __forceinline__ float gexp_asm(float x) {
  float r; asm("v_exp_f32 %0, %1" : "=v"(r) : "v"(x)); return r;
}
#define GEXP(x) gexp_asm(x)
#endif

__device__ __forceinline__ unsigned short f2bf(float x) {
  union { float f; unsigned u; } v; v.f = x;
  unsigned r = v.u + 0x7fffu + ((v.u >> 16) & 1u);
  return (unsigned short)(r >> 16);
}
__device__ __forceinline__ unsigned cvtpk(float lo, float hi) {
  unsigned r;
  asm("v_cvt_pk_bf16_f32 %0, %1, %2" : "=v"(r) : "v"(lo), "v"(hi));
  return r;
}
__device__ __forceinline__ float rcpa(float x) {
  float r; asm("v_rcp_f32 %0, %1" : "=v"(r) : "v"(x)); return r;
}
// tanh-form GELU: x/(1+exp2(x*(C0+C1*x^2)))
__device__ __forceinline__ float gelu_fast(float x) {
  float x2 = x * x;
  float w = __builtin_fmaf(x2, -0.1029488f, -2.3022078f);
  float e = GEXP(x * w);
  return x * rcpa(e + 1.0f);
}

// ---------------- prep: weights->bf16 (W1 pre-scaled), packed gaussian params -
__global__ void prep_kernel(const float* __restrict__ means, const float* __restrict__ stds,
                            const float* __restrict__ W1, const float* __restrict__ W2,
                            unsigned short* __restrict__ W1bf, unsigned short* __restrict__ W2bf,
                            float* __restrict__ prm /* [512][2]: mis2, is2 */) {
  int t = blockIdx.x * blockDim.x + threadIdx.x;
  int stride = gridDim.x * blockDim.x;
  for (int i = t; i < 512 * 512; i += stride) W1bf[i] = f2bf(W1[i] * W1_SCALE);
  for (int i = t; i < 32 * 512; i += stride) W2bf[i] = f2bf(W2[i]);
  for (int i = t; i < 512; i += stride) {
    float s = fabsf(stds[i]) + 0.01f;
    float is2 = (1.0f / s) * IS2_SCALE;
    prm[2 * i] = -means[i] * is2;        // mis2
    prm[2 * i + 1] = is2;                // is2  (g' = is2*exp2(-u^2); coef folded into W1)
  }
}

// ---------------- fused main kernel ------------------------------------------
// 512 threads = 8 waves (2M x 4N), 64 flat rows per block; wave = 32rows x 128cols.
// A (gaussian) in registers (B-frag reused across 2 row-frags -> 8 ds_read/iter);
// B (W1 32KB k-slice) double-buffered in LDS via global_load_lds; counted vmcnt
// + two raw barriers per iter (T3/T4, proven in R8).
__global__ __launch_bounds__(512, 4) void fused_kernel(
    const float* __restrict__ rpe, const unsigned short* __restrict__ W1bf,
    const unsigned short* __restrict__ W2bf, const float* __restrict__ prm,
    const float* __restrict__ b1, const float* __restrict__ b2,
    float* __restrict__ out) {
  __shared__ __attribute__((aligned(16))) char lds[65536 + 4096 + 1024 + 2048];
  // [0,64K): B dbuf (2x32KB) -> h[64][512] bf16 -> out[64][33] f32
  float* prm_s = (float*)(lds + 65536);                  // [512][2] = 4KB
  float* rpe_s = (float*)(lds + 65536 + 4096);           // [64][4]  = 1KB
  float* b1_s  = (float*)(lds + 65536 + 4096 + 1024);    // [512]    = 2KB

  const int tid = threadIdx.x;
  const int rb = blockIdx.x * 64;

  if (tid < 256) rpe_s[tid] = rpe[rb * 4 + tid];
  for (int i = tid; i < 1024; i += 512) prm_s[i] = prm[i];
  b1_s[tid] = b1[tid];

  int goff[4];
#pragma unroll
  for (int i = 0; i < 4; ++i) {
    int c = i * 512 + tid;
    int j = ((c >> 6) << 4) + (c & 15);
    goff[i] = j * 512 + ((c >> 4) & 3) * 8;
  }
  const char* Wc = (const char*)W1bf;

#define STAGE(buf, kb)                                                          \
  {                                                                             \
    _Pragma("unroll") for (int i_ = 0; i_ < 4; ++i_) {                          \
      const void* gp = (const void*)(Wc + (size_t)goff[i_] * 2 + (kb) * 64);    \
      void* lp = (void*)(lds + (buf) * 32768 + i_ * 8192 + tid * 16);           \
      __builtin_amdgcn_global_load_lds(                                         \
          (const __attribute__((address_space(1))) void*)gp,                    \
          (__attribute__((address_space(3))) void*)lp, 16, 0, 0);               \
    }                                                                           \
  }

  STAGE(0, 0);
  __syncthreads();   // full drain: rpe/prm/b1 + B slice 0 collectively ready

  const int w = tid >> 6, l = tid & 63;
  const int lr = l & 15, lg = l >> 4;
  const int mw = w >> 2, nw = w & 3;     // 2 M-waves x 4 N-waves
  const int r0 = mw * 32 + lr;           // A rows r0 and r0+16

  // hoisted per-lane rpe values (8 floats, read once)
  const f32x4 xa = *(const f32x4*)&rpe_s[r0 * 4];
  const f32x4 xb = *(const f32x4*)&rpe_s[(r0 + 16) * 4];

  f32x4 zv = {0.f, 0.f, 0.f, 0.f};
  f32x4 acc[2][8];
#pragma unroll
  for (int mf = 0; mf < 2; ++mf)
#pragma unroll
    for (int nf = 0; nf < 8; ++nf) acc[mf][nf] = zv;

  const f32x4* prm4 = (const f32x4*)prm_s;   // [256] of {mis2,is2,mis2,is2}
  int cur = 0;

#pragma unroll
  for (int kb = 0; kb < 16; ++kb) {
    if (kb < 15) {
      STAGE(cur ^ 1, kb + 1);
      asm volatile("s_waitcnt vmcnt(4)" ::: "memory");
    } else {
      asm volatile("s_waitcnt vmcnt(0)" ::: "memory");
    }
    __builtin_amdgcn_s_barrier();            // barrier 1: cur fully staged
    __builtin_amdgcn_sched_barrier(0);

    // ---- A fragments: 16 gaussians (2 rows x 8 k) per lane
    const int k0 = kb * 32 + lg * 8;
    const float x0 = xa[kb >> 2];
    const float x1 = xb[kb >> 2];
    unsigned pk0[4], pk1[4];
#pragma unroll
    for (int q = 0; q < 4; ++q) {
      f32x4 P = prm4[(k0 >> 1) + q];     // {mis2_e, is2_e, mis2_o, is2_o}
      float u00 = __builtin_fmaf(x0, P[1], P[0]);
      float u01 = __builtin_fmaf(x0, P[3], P[2]);
      float u10 = __builtin_fmaf(x1, P[1], P[0]);
      float u11 = __builtin_fmaf(x1, P[3], P[2]);
      pk0[q] = cvtpk(P[1] * GEXP(-(u00 * u00)), P[3] * GEXP(-(u01 * u01)));
      pk1[q] = cvtpk(P[1] * GEXP(-(u10 * u10)), P[3] * GEXP(-(u11 * u11)));
    }
    u32x4 av0 = {pk0[0], pk0[1], pk0[2], pk0[3]};
    u32x4 av1 = {pk1[0], pk1[1], pk1[2], pk1[3]};
    bfrag8 a0 = __builtin_bit_cast(bfrag8, av0);
    bfrag8 a1 = __builtin_bit_cast(bfrag8, av1);

    // ---- B fragments from LDS (8 reads, each reused by both row-frags)
    const char* Bbase = lds + cur * 32768 + nw * 8192 + lg * 256 + lr * 16;
    __builtin_amdgcn_s_setprio(1);
#pragma unroll
    for (int nf = 0; nf < 8; ++nf) {
      bfrag8 b = *(const bfrag8*)(Bbase + nf * 1024);
      acc[0][nf] = __builtin_amdgcn_mfma_f32_16x16x32_bf16(a0, b, acc[0][nf], 0, 0, 0);
      acc[1][nf] = __builtin_amdgcn_mfma_f32_16x16x32_bf16(a1, b, acc[1][nf], 0, 0, 0);
    }
    __builtin_amdgcn_s_setprio(0);

    __builtin_amdgcn_s_barrier();            // barrier 2: cur reads done
    cur ^= 1;
  }

  // ---- bias + fast GELU -> h in LDS [64][512] bf16, XOR-swizzled rows
  unsigned short* hbuf = (unsigned short*)lds;
#pragma unroll
  for (int mf = 0; mf < 2; ++mf) {
#pragma unroll
    for (int nf = 0; nf < 8; nf += 2) {
      int col0 = nw * 128 + nf * 16 + lr;
      int col1 = col0 + 16;
      float bb0 = b1_s[col0], bb1 = b1_s[col1];
#pragma unroll
      for (int bi = 0; bi < 4; ++bi) {
        float g0 = gelu_fast(acc[mf][nf][bi] + bb0);
        float g1 = gelu_fast(acc[mf][nf + 1][bi] + bb1);
        unsigned pr = cvtpk(g0, g1);
        int hrow = mw * 32 + mf * 16 + lg * 4 + bi;
        int base = hrow * 1024, sw = (hrow & 7) << 4;
        *(unsigned short*)((char*)hbuf + base + ((col0 * 2) ^ sw)) = (unsigned short)pr;
        *(unsigned short*)((char*)hbuf + base + ((col1 * 2) ^ sw)) = (unsigned short)(pr >> 16);
      }
    }
  }
  __syncthreads();

  // ---- GEMM2: out[64][32] = h @ W2^T. 8 waves: 4(M) x 2(N).
  const int mf2 = w >> 1, nf2 = w & 1;
  f32x4 acc2 = zv;
  const int row2 = mf2 * 16 + lr;
  for (int kb = 0; kb < 16; ++kb) {
    int cb = (kb * 64 + lg * 16) ^ ((row2 & 7) << 4);
    bfrag8 a = *(const bfrag8*)((char*)hbuf + row2 * 1024 + cb);
    bfrag8 b = *(const bfrag8*)(W2bf + (size_t)(nf2 * 16 + lr) * 512 + kb * 32 + lg * 8);
    acc2 = __builtin_amdgcn_mfma_f32_16x16x32_bf16(a, b, acc2, 0, 0, 0);
  }
  float b2v = b2[nf2 * 16 + lr];
  __syncthreads();                     // all h reads done -> safe to overlay

  float* ob = (float*)lds;             // [64][33] padded
#pragma unroll
  for (int bi = 0; bi < 4; ++bi)
    ob[(mf2 * 16 + lg * 4 + bi) * 33 + (nf2 * 16 + lr)] = acc2[bi] + b2v;
  __syncthreads();

  // ---- store transposed: out[b][o][m][n], 64 contiguous n per head
  const int bI = rb >> 16, mI = (rb >> 8) & 255, n0 = rb & 255;
  float* obase = out + ((size_t)(bI * 32) * 256 + mI) * 256 + n0;
#pragma unroll
  for (int p = 0; p < 4; ++p) {
    int e = tid + p * 512;             // 0..2047
    int o = e >> 6, i = e & 63;
    obase[(size_t)o * 65536 + i] = ob[i * 33 + o];
  }
#undef STAGE
}

// ---------------- launch ------------------------------------------------------
extern "C" void kernel_launch(void* const* d_in, const int* in_sizes, int n_in,
                              void* d_out, int out_size, void* d_ws, size_t ws_size,
                              hipStream_t stream) {
  const float* rpe   = (const float*)d_in[0];
  const float* means = (const float*)d_in[1];
  const float* stds  = (const float*)d_in[2];
  const float* W1    = (const float*)d_in[3];
  const float* b1    = (const float*)d_in[4];
  const float* W2    = (const float*)d_in[5];
  const float* b2    = (const float*)d_in[6];
  float* out = (float*)d_out;

  char* ws = (char*)d_ws;
  unsigned short* W1bf = (unsigned short*)ws;             // 512*512*2 = 524288 B
  unsigned short* W2bf = (unsigned short*)(ws + 524288);  // 32*512*2  =  32768 B
  float* prm = (float*)(ws + 557056);                     // 512*2*4   =   4096 B

  prep_kernel<<<256, 256, 0, stream>>>(means, stds, W1, W2, W1bf, W2bf, prm);
  fused_kernel<<<4096, 512, 0, stream>>>(rpe, W1bf, W2bf, prm, b1, b2, out);
}

// Round 12
// 276.041 us; speedup vs baseline: 1.2066x; 1.2066x over previous
//
#include <hip/hip_runtime.h>
#include <hip/hip_bf16.h>

typedef __attribute__((ext_vector_type(8))) short bfrag8;
typedef __attribute__((ext_vector_type(4))) float f32x4;
typedef __attribute__((ext_vector_type(4))) unsigned int u32x4;

#define IS2_SCALE 0.84932180028801907f   /* sqrt(0.5*log2(e)): exp2(-(u)^2)=exp(-t^2/2) */
#define W1_SCALE  0.46971724f            /* 1/(sqrt(2*3.14159)*IS2_SCALE): folds coef into W1 */

#if __has_builtin(__builtin_amdgcn_exp2f)
#define GEXP(x) __builtin_amdgcn_exp2f(x)
#else
__device__ __forceinline__ float gexp_asm(float x) {
  float r; asm("v_exp_f32 %0, %1" : "=v"(r) : "v"(x)); return r;
}
#define GEXP(x) gexp_asm(x)
#endif

__device__ __forceinline__ unsigned short f2bf(float x) {
  union { float f; unsigned u; } v; v.f = x;
  unsigned r = v.u + 0x7fffu + ((v.u >> 16) & 1u);
  return (unsigned short)(r >> 16);
}
__device__ __forceinline__ unsigned cvtpk(float lo, float hi) {
  unsigned r;
  asm("v_cvt_pk_bf16_f32 %0, %1, %2" : "=v"(r) : "v"(lo), "v"(hi));
  return r;
}
__device__ __forceinline__ float rcpa(float x) {
  float r; asm("v_rcp_f32 %0, %1" : "=v"(r) : "v"(x)); return r;
}
// tanh-form GELU: x/(1+exp2(x*(C0+C1*x^2)))
__device__ __forceinline__ float gelu_fast(float x) {
  float x2 = x * x;
  float w = __builtin_fmaf(x2, -0.1029488f, -2.3022078f);
  float e = GEXP(x * w);
  return x * rcpa(e + 1.0f);
}

// ---------------- prep: weights->bf16 (W1 pre-scaled), packed gaussian params -
__global__ void prep_kernel(const float* __restrict__ means, const float* __restrict__ stds,
                            const float* __restrict__ W1, const float* __restrict__ W2,
                            unsigned short* __restrict__ W1bf, unsigned short* __restrict__ W2bf,
                            float* __restrict__ prm /* [512][2]: mis2, is2 */) {
  int t = blockIdx.x * blockDim.x + threadIdx.x;
  int stride = gridDim.x * blockDim.x;
  for (int i = t; i < 512 * 512; i += stride) W1bf[i] = f2bf(W1[i] * W1_SCALE);
  for (int i = t; i < 32 * 512; i += stride) W2bf[i] = f2bf(W2[i]);
  for (int i = t; i < 512; i += stride) {
    float s = fabsf(stds[i]) + 0.01f;
    float is2 = (1.0f / s) * IS2_SCALE;
    prm[2 * i] = -means[i] * is2;        // mis2
    prm[2 * i + 1] = is2;                // is2  (g' = is2*exp2(-u^2); coef folded into W1)
  }
}

// ---------------- fused main kernel ------------------------------------------
// 1024 threads = 16 waves (4M x 4N), 128 flat rows per block; wave = 32r x 128c.
// Doubled work per barrier-pair vs the 64-row version: 16 MFMA/wave/iter, same
// 32KB stage -> per-CU LDS traffic halves, barrier overhead amortizes 2x.
// A computed in registers BEFORE the vmcnt wait (covers staging latency, R8
// ordering); counted vmcnt + two raw barriers per iter (T3/T4).
__global__ __launch_bounds__(1024, 4) void fused_kernel(
    const float* __restrict__ rpe, const unsigned short* __restrict__ W1bf,
    const unsigned short* __restrict__ W2bf, const float* __restrict__ prm,
    const float* __restrict__ b1, const float* __restrict__ b2,
    float* __restrict__ out) {
  __shared__ __attribute__((aligned(16))) char lds[131072 + 4096 + 2048 + 2048];
  // [0,128K): B dbuf (2x32KB) -> h[128][512] bf16 -> out[128][33] f32
  float* prm_s = (float*)(lds + 131072);                  // [512][2] = 4KB
  float* rpe_s = (float*)(lds + 131072 + 4096);           // [128][4] = 2KB
  float* b1_s  = (float*)(lds + 131072 + 4096 + 2048);    // [512]    = 2KB

  const int tid = threadIdx.x;
  const int rb = blockIdx.x * 128;

  if (tid < 512) rpe_s[tid] = rpe[rb * 4 + tid];
  prm_s[tid] = prm[tid];                 // 1024 floats, one round
  if (tid < 512) b1_s[tid] = b1[tid];

  int goff[2];
#pragma unroll
  for (int i = 0; i < 2; ++i) {
    int c = i * 1024 + tid;
    int j = ((c >> 6) << 4) + (c & 15);
    goff[i] = j * 512 + ((c >> 4) & 3) * 8;
  }
  const char* Wc = (const char*)W1bf;

#define STAGE(buf, kb)                                                          \
  {                                                                             \
    _Pragma("unroll") for (int i_ = 0; i_ < 2; ++i_) {                          \
      const void* gp = (const void*)(Wc + (size_t)goff[i_] * 2 + (kb) * 64);    \
      void* lp = (void*)(lds + (buf) * 32768 + i_ * 16384 + tid * 16);          \
      __builtin_amdgcn_global_load_lds(                                         \
          (const __attribute__((address_space(1))) void*)gp,                    \
          (__attribute__((address_space(3))) void*)lp, 16, 0, 0);               \
    }                                                                           \
  }

  STAGE(0, 0);
  __syncthreads();   // full drain: rpe/prm/b1 + B slice 0 collectively ready

  const int w = tid >> 6, l = tid & 63;
  const int lr = l & 15, lg = l >> 4;
  const int mw = w >> 2, nw = w & 3;     // 4 M-waves x 4 N-waves
  const int r0 = mw * 32 + lr;           // A rows r0 and r0+16

  // hoisted per-lane rpe values (read once)
  const f32x4 xa = *(const f32x4*)&rpe_s[r0 * 4];
  const f32x4 xb = *(const f32x4*)&rpe_s[(r0 + 16) * 4];

  f32x4 zv = {0.f, 0.f, 0.f, 0.f};
  f32x4 acc[2][8];
#pragma unroll
  for (int mf = 0; mf < 2; ++mf)
#pragma unroll
    for (int nf = 0; nf < 8; ++nf) acc[mf][nf] = zv;

  const f32x4* prm4 = (const f32x4*)prm_s;   // [256] of {mis2,is2,mis2,is2}
  int cur = 0;

#pragma unroll
  for (int kb = 0; kb < 16; ++kb) {
    if (kb < 15) STAGE(cur ^ 1, kb + 1);

    // ---- A fragments (BEFORE the wait: covers staging latency)
    const int k0 = kb * 32 + lg * 8;
    const float x0 = xa[kb >> 2];
    const float x1 = xb[kb >> 2];
    unsigned pk0[4], pk1[4];
#pragma unroll
    for (int q = 0; q < 4; ++q) {
      f32x4 P = prm4[(k0 >> 1) + q];     // {mis2_e, is2_e, mis2_o, is2_o}
      float u00 = __builtin_fmaf(x0, P[1], P[0]);
      float u01 = __builtin_fmaf(x0, P[3], P[2]);
      float u10 = __builtin_fmaf(x1, P[1], P[0]);
      float u11 = __builtin_fmaf(x1, P[3], P[2]);
      pk0[q] = cvtpk(P[1] * GEXP(-(u00 * u00)), P[3] * GEXP(-(u01 * u01)));
      pk1[q] = cvtpk(P[1] * GEXP(-(u10 * u10)), P[3] * GEXP(-(u11 * u11)));
    }
    u32x4 av0 = {pk0[0], pk0[1], pk0[2], pk0[3]};
    u32x4 av1 = {pk1[0], pk1[1], pk1[2], pk1[3]};
    bfrag8 a0 = __builtin_bit_cast(bfrag8, av0);
    bfrag8 a1 = __builtin_bit_cast(bfrag8, av1);

    // ---- wait for OWN slice of buffer cur; barrier => collectively staged
    if (kb < 15) {
      asm volatile("s_waitcnt vmcnt(2)" ::: "memory");
    } else {
      asm volatile("s_waitcnt vmcnt(0)" ::: "memory");
    }
    __builtin_amdgcn_s_barrier();            // barrier 1: cur fully staged
    __builtin_amdgcn_sched_barrier(0);

    // ---- B fragments from LDS (8 reads, each reused by both row-frags)
    const char* Bbase = lds + cur * 32768 + nw * 8192 + lg * 256 + lr * 16;
    __builtin_amdgcn_s_setprio(1);
#pragma unroll
    for (int nf = 0; nf < 8; ++nf) {
      bfrag8 b = *(const bfrag8*)(Bbase + nf * 1024);
      acc[0][nf] = __builtin_amdgcn_mfma_f32_16x16x32_bf16(a0, b, acc[0][nf], 0, 0, 0);
      acc[1][nf] = __builtin_amdgcn_mfma_f32_16x16x32_bf16(a1, b, acc[1][nf], 0, 0, 0);
    }
    __builtin_amdgcn_s_setprio(0);

    __builtin_amdgcn_s_barrier();            // barrier 2: cur reads done
    cur ^= 1;
  }

  // ---- bias + fast GELU -> h in LDS [128][512] bf16, XOR-swizzled rows
  unsigned short* hbuf = (unsigned short*)lds;
#pragma unroll
  for (int mf = 0; mf < 2; ++mf) {
#pragma unroll
    for (int nf = 0; nf < 8; nf += 2) {
      int col0 = nw * 128 + nf * 16 + lr;
      int col1 = col0 + 16;
      float bb0 = b1_s[col0], bb1 = b1_s[col1];
#pragma unroll
      for (int bi = 0; bi < 4; ++bi) {
        float g0 = gelu_fast(acc[mf][nf][bi] + bb0);
        float g1 = gelu_fast(acc[mf][nf + 1][bi] + bb1);
        unsigned pr = cvtpk(g0, g1);
        int hrow = mw * 32 + mf * 16 + lg * 4 + bi;
        int base = hrow * 1024, sw = (hrow & 7) << 4;
        *(unsigned short*)((char*)hbuf + base + ((col0 * 2) ^ sw)) = (unsigned short)pr;
        *(unsigned short*)((char*)hbuf + base + ((col1 * 2) ^ sw)) = (unsigned short)(pr >> 16);
      }
    }
  }
  __syncthreads();

  // ---- GEMM2: out[128][32] = h @ W2^T. 16 waves: 8(row-tiles) x 2(col-tiles).
  const int rt = w >> 1, ct = w & 1;
  f32x4 acc2 = zv;
  const int row2 = rt * 16 + lr;
  for (int kb = 0; kb < 16; ++kb) {
    int cb = (kb * 64 + lg * 16) ^ ((row2 & 7) << 4);
    bfrag8 a = *(const bfrag8*)((char*)hbuf + row2 * 1024 + cb);
    bfrag8 b = *(const bfrag8*)(W2bf + (size_t)(ct * 16 + lr) * 512 + kb * 32 + lg * 8);
    acc2 = __builtin_amdgcn_mfma_f32_16x16x32_bf16(a, b, acc2, 0, 0, 0);
  }
  float b2v = b2[ct * 16 + lr];
  __syncthreads();                     // all h reads done -> safe to overlay

  float* ob = (float*)lds;             // [128][33] padded f32
#pragma unroll
  for (int bi = 0; bi < 4; ++bi)
    ob[(rt * 16 + lg * 4 + bi) * 33 + (ct * 16 + lr)] = acc2[bi] + b2v;
  __syncthreads();

  // ---- store transposed: out[b][o][m][n], 128 contiguous n per head
  const int bI = rb >> 16, mI = (rb >> 8) & 255, n0 = rb & 255;
  float* obase = out + ((size_t)(bI * 32) * 256 + mI) * 256 + n0;
#pragma unroll
  for (int p = 0; p < 4; ++p) {
    int e = tid + p * 1024;            // 0..4095
    int o = e >> 7, i = e & 127;
    obase[(size_t)o * 65536 + i] = ob[i * 33 + o];
  }
#undef STAGE
}

// ---------------- launch ------------------------------------------------------
extern "C" void kernel_launch(void* const* d_in, const int* in_sizes, int n_in,
                              void* d_out, int out_size, void* d_ws, size_t ws_size,
                              hipStream_t stream) {
  const float* rpe   = (const float*)d_in[0];
  const float* means = (const float*)d_in[1];
  const float* stds  = (const float*)d_in[2];
  const float* W1    = (const float*)d_in[3];
  const float* b1    = (const float*)d_in[4];
  const float* W2    = (const float*)d_in[5];
  const float* b2    = (const float*)d_in[6];
  float* out = (float*)d_out;

  char* ws = (char*)d_ws;
  unsigned short* W1bf = (unsigned short*)ws;             // 512*512*2 = 524288 B
  unsigned short* W2bf = (unsigned short*)(ws + 524288);  // 32*512*2  =  32768 B
  float* prm = (float*)(ws + 557056);                     // 512*2*4   =   4096 B

  prep_kernel<<<256, 256, 0, stream>>>(means, stds, W1, W2, W1bf, W2bf, prm);
  fused_kernel<<<2048, 1024, 0, stream>>>(rpe, W1bf, W2bf, prm, b1, b2, out);
}